// Round 14
// baseline (628.205 us; speedup 1.0000x reference)
//
#include <hip/hip_runtime.h>
#include <math.h>

#define Hdim 4096
#define Vdim 32000
#define MTOK 2048
#define NSTRIPS 250        /* 32000/128 */
#define NMT 16             /* 2048/128 */
#define NKT4 32            /* 4096/128 MX K-tiles */
#define TILEF4 8192        /* 128 rows x 128 fp4 = 8 KB (64 B row stride) */

#define IGNORE_INDEX (-100)
#define BETA 0.1f
#define ALPHA 1.0f
#define SIMPO_GAMMA 0.5f
#define LABEL_SMOOTHING 0.0f

#define XSCALE 2.0f
#define WSCALE 100.0f
#define INV_SCALE (1.0f / (XSCALE * WSCALE))

#define WT4_BYTES ((size_t)NSTRIPS * NKT4 * TILEF4)  /* 65,536,000 */
#define XT4_BYTES ((size_t)NMT * NKT4 * TILEF4)      /*  4,194,304 */

typedef __attribute__((ext_vector_type(8))) short bf16x8;
typedef __attribute__((ext_vector_type(4))) float f32x4;
typedef __attribute__((ext_vector_type(8))) int i32x8;
typedef __attribute__((ext_vector_type(4))) int i32x4;

static __device__ __forceinline__ short f2bf(float f) {
    unsigned int u = __float_as_uint(f);
    u = u + 0x7fffu + ((u >> 16) & 1u);
    return (short)(u >> 16);
}

static __device__ __forceinline__ f32x4 vmax4(f32x4 a, f32x4 b) {
    f32x4 r;
    r[0] = fmaxf(a[0], b[0]); r[1] = fmaxf(a[1], b[1]);
    r[2] = fmaxf(a[2], b[2]); r[3] = fmaxf(a[3], b[3]);
    return r;
}

static __device__ __forceinline__ void gload_lds16(const void* g, void* l) {
    __builtin_amdgcn_global_load_lds(
        (const __attribute__((address_space(1))) unsigned int*)g,
        (__attribute__((address_space(3))) unsigned int*)l,
        16, 0, 0);
}

// ---- f32 -> OCP e2m1 fp4, RNE. Magnitudes {0,.5,1,1.5,2,3,4,6}. ----------
static __device__ __forceinline__ unsigned int f2e2m1(float f) {
    const unsigned s = (__float_as_uint(f) >> 28) & 0x8u;   // sign -> bit 3
    const float a = fabsf(f);
    unsigned c;
    if      (a <= 0.25f) c = 0u;
    else if (a <  0.75f) c = 1u;
    else if (a <= 1.25f) c = 2u;
    else if (a <  1.75f) c = 3u;
    else if (a <= 2.5f)  c = 4u;
    else if (a <  3.5f)  c = 5u;
    else if (a <= 5.0f)  c = 6u;
    else                 c = 7u;
    return s | c;
}

static __device__ __forceinline__ unsigned int pack8_e2m1(const float* v, float S) {
    unsigned r = 0;
#pragma unroll
    for (int i = 0; i < 8; i++) r |= f2e2m1(v[i] * S) << (4 * i);
    return r;
}

// ---------------------------------------------------------------------------
// Merged conversion: f32 -> e2m1 K-tiles (128 rows x 128 fp4 = 8 KB).
// Blocks [0, 16000): W (pre-scaled x100). Blocks [16000, 17024): x (x2).
// Row = 4 slots x 16 B (32 fp4 each); slot involution p = s ^ ((row>>1)&3)
// (64 B row stride -> round-6's measured-0-conflict bank phasing).
// ---------------------------------------------------------------------------
__global__ void k_conv4(const float* __restrict__ W, const float* __restrict__ x,
                        char* __restrict__ Wt, char* __restrict__ Xt)
{
    const unsigned int bidx = blockIdx.x;
    const float* srcbase;
    char* dstbase;
    unsigned int gc;
    float S;
    if (bidx < 16000u) {
        gc = bidx * 256 + threadIdx.x;          // < 4,096,000
        srcbase = W; dstbase = Wt; S = WSCALE;
    } else {
        gc = (bidx - 16000u) * 256 + threadIdx.x;  // < 262,144
        srcbase = x; dstbase = Xt; S = XSCALE;
    }
    const unsigned int tile = gc >> 9;          // (rt*32 + kt), 512 chunks/tile
    const unsigned int o = gc & 511u;
    const unsigned int row = o >> 2, p = o & 3u;
    const unsigned int s = p ^ ((row >> 1) & 3u);   // source k-slot (32 elems)
    const unsigned int rt = tile >> 5, kt = tile & 31u;
    const float* src = srcbase + (size_t)(rt * 128 + row) * Hdim + kt * 128 + s * 32;
    float buf[32];
#pragma unroll
    for (int i = 0; i < 8; i++)
        *reinterpret_cast<float4*>(&buf[i * 4]) = *(const float4*)(src + i * 4);
    uint4 v;
    v.x = pack8_e2m1(buf +  0, S);
    v.y = pack8_e2m1(buf +  8, S);
    v.z = pack8_e2m1(buf + 16, S);
    v.w = pack8_e2m1(buf + 24, S);
    *reinterpret_cast<uint4*>(dstbase + (size_t)tile * TILEF4 + o * 16) = v;
}

// ---------------------------------------------------------------------------
// MX-fp4 GEMM, m97 structure (measured ~2900 TF here, = m153 ladder ref):
// 128x128 tile, K-step 128, single 16 KB LDS buffer, 4 waves, 2-barrier loop,
// global_load_lds w16, 6 blocks/CU (occupancy lever: LDS 101 KB, VGPR<=85).
// One ds_read_b128 per fragment. mfma_scale 16x16x128 fp4 (cbsz=blgp=4),
// neutral scales. Fused LSE epilogue.
// ---------------------------------------------------------------------------
__global__ __launch_bounds__(256, 6)
void k_gemm_mx4(const char* __restrict__ Wt, const char* __restrict__ Xt,
                const int* __restrict__ y,
                float* __restrict__ pmax, float* __restrict__ psum,
                float* __restrict__ tgt)
{
    const int bid = blockIdx.x;
    // XCD-bijective swizzle: 4000 = 8 x 500, vt-major chunks per XCD.
    const int orig = (bid & 7) * 500 + (bid >> 3);
    const int vt = orig >> 4;          // 0..249
    const int mt = orig & 15;          // 0..15
    const int m0 = mt * 128, v0 = vt * 128;
    const int tid = threadIdx.x, lane = tid & 63, wid = tid >> 6;
    const int wm = (wid >> 1) * 64;
    const int wv = (wid & 1) * 64;

    __shared__ char lsA[TILEF4];
    __shared__ char lsB[TILEF4];
    __shared__ int   yloc[128];
    __shared__ float wredM[4][64];
    __shared__ float wredS[4][64];

    if (tid < 128) yloc[tid] = y[m0 + tid];

    f32x4 acc[4][4];
#pragma unroll
    for (int i = 0; i < 4; i++)
#pragma unroll
        for (int j = 0; j < 4; j++) acc[i][j] = (f32x4)(0.0f);

    const char* gA = Xt + ((size_t)mt * NKT4) * TILEF4;
    const char* gB = Wt + ((size_t)vt * NKT4) * TILEF4;

    // Per-lane LDS byte offsets: lane's k-group g = lane>>4 (32 fp4 = 16 B),
    // at physical slot (g ^ ((row>>1)&3)), 64 B rows.
    const int g = lane >> 4;
    int oA[4], oB[4];
#pragma unroll
    for (int rf = 0; rf < 4; rf++) {
        const int row = wm + rf * 16 + (lane & 15);
        oA[rf] = row * 64 + ((g ^ ((row >> 1) & 3)) << 4);
    }
#pragma unroll
    for (int cf = 0; cf < 4; cf++) {
        const int row = wv + cf * 16 + (lane & 15);
        oB[cf] = row * 64 + ((g ^ ((row >> 1) & 3)) << 4);
    }

#pragma unroll 1
    for (int kt = 0; kt < NKT4; ++kt) {
        __syncthreads();
        const char* sA = gA + (size_t)kt * TILEF4;
        const char* sB = gB + (size_t)kt * TILEF4;
        gload_lds16(sA + tid * 16,        lsA + tid * 16);
        gload_lds16(sA + 4096 + tid * 16, lsA + 4096 + tid * 16);
        gload_lds16(sB + tid * 16,        lsB + tid * 16);
        gload_lds16(sB + 4096 + tid * 16, lsB + 4096 + tid * 16);
        __syncthreads();

        i32x8 aF[4], bF[4];
#pragma unroll
        for (int rf = 0; rf < 4; rf++) {
            i32x4 d = *(const i32x4*)(lsA + oA[rf]);
            i32x8 v;
            v[0] = d[0]; v[1] = d[1]; v[2] = d[2]; v[3] = d[3];
            v[4] = 0; v[5] = 0; v[6] = 0; v[7] = 0;
            aF[rf] = v;
        }
#pragma unroll
        for (int cf = 0; cf < 4; cf++) {
            i32x4 d = *(const i32x4*)(lsB + oB[cf]);
            i32x8 v;
            v[0] = d[0]; v[1] = d[1]; v[2] = d[2]; v[3] = d[3];
            v[4] = 0; v[5] = 0; v[6] = 0; v[7] = 0;
            bF[cf] = v;
        }
#pragma unroll
        for (int rf = 0; rf < 4; rf++)
#pragma unroll
            for (int cf = 0; cf < 4; cf++)
                acc[rf][cf] = __builtin_amdgcn_mfma_scale_f32_16x16x128_f8f6f4(
                    aF[rf], bF[cf], acc[rf][cf],
                    4, 4,                 // cbsz: A=fp4, blgp: B=fp4
                    0, 0x7F7F7F7F,        // opsel_a, scale_a = 2^0
                    0, 0x7F7F7F7F);       // opsel_b, scale_b = 2^0
    }

    __syncthreads();

    // undo pre-scales (x2 * 100)
#pragma unroll
    for (int i = 0; i < 4; i++)
#pragma unroll
        for (int j = 0; j < 4; j++)
#pragma unroll
            for (int r = 0; r < 4; r++) acc[i][j][r] *= INV_SCALE;

    // ---- target-logit extraction (C layout m89: col=lane&15, row=(lane>>4)*4+r)
    {
        const int colbase = v0 + wv + (lane & 15);
        const int rbase = wm + ((lane >> 4) << 2);
#pragma unroll
        for (int i = 0; i < 4; i++) {
#pragma unroll
            for (int r = 0; r < 4; r++) {
                const int rloc = rbase + i * 16 + r;
                const int yv = yloc[rloc];
#pragma unroll
                for (int j = 0; j < 4; j++)
                    if (yv == colbase + j * 16) tgt[m0 + rloc] = acc[i][j][r];
            }
        }
    }

    // ---- per-row max / sum(exp) over this wave's 64 cols
    f32x4 rm[4], rs[4];
#pragma unroll
    for (int i = 0; i < 4; i++) {
        rm[i] = acc[i][0];
#pragma unroll
        for (int j = 1; j < 4; j++) rm[i] = vmax4(rm[i], acc[i][j]);
#pragma unroll
        for (int off = 1; off < 16; off <<= 1) {
            f32x4 o;
#pragma unroll
            for (int r = 0; r < 4; r++) o[r] = __shfl_xor(rm[i][r], off);
            rm[i] = vmax4(rm[i], o);
        }
    }
#pragma unroll
    for (int i = 0; i < 4; i++) {
        f32x4 s = (f32x4)(0.0f);
#pragma unroll
        for (int j = 0; j < 4; j++)
#pragma unroll
            for (int r = 0; r < 4; r++) s[r] += expf(acc[i][j][r] - rm[i][r]);
#pragma unroll
        for (int off = 1; off < 16; off <<= 1) {
#pragma unroll
            for (int r = 0; r < 4; r++) s[r] += __shfl_xor(s[r], off);
        }
        rs[i] = s;
    }
    if ((lane & 15) == 0) {
        const int gq = lane >> 4;
#pragma unroll
        for (int i = 0; i < 4; i++)
#pragma unroll
            for (int r = 0; r < 4; r++) {
                wredM[wid][i * 16 + gq * 4 + r] = rm[i][r];
                wredS[wid][i * 16 + gq * 4 + r] = rs[i][r];
            }
    }
    __syncthreads();
    if (tid < 128) {
        const int r = tid;
        const int gh = r >> 6;
        const int rl = r & 63;
        const float ma = wredM[2 * gh][rl],  mb = wredM[2 * gh + 1][rl];
        const float sa = wredS[2 * gh][rl],  sb = wredS[2 * gh + 1][rl];
        const float M = fmaxf(ma, mb);
        const float S = sa * expf(ma - M) + sb * expf(mb - M);
        pmax[(size_t)vt * MTOK + m0 + r] = M;
        psum[(size_t)vt * MTOK + m0 + r] = S;
    }
}

// ---------------------------------------------------------------------------
// Finalize: 4 lanes per token (two-phase max/sum, shfl_xor merge).
// grid 32 x 256: block handles 64 tokens.
// ---------------------------------------------------------------------------
__global__ void k_finalize4(const float* __restrict__ pmax, const float* __restrict__ psum,
                            const float* __restrict__ tgt, float* __restrict__ logp,
                            int nstrips)
{
    const int tid = threadIdx.x;
    const int m = blockIdx.x * 64 + (tid >> 2);   // token
    const int q = tid & 3;                        // lane's strip phase
    if (m >= MTOK) return;

    float M = -INFINITY;
    for (int s = q; s < nstrips; s += 4) M = fmaxf(M, pmax[(size_t)s * MTOK + m]);
    M = fmaxf(M, __shfl_xor(M, 1));
    M = fmaxf(M, __shfl_xor(M, 2));

    float S = 0.0f;
    for (int s = q; s < nstrips; s += 4)
        S += psum[(size_t)s * MTOK + m] * expf(pmax[(size_t)s * MTOK + m] - M);
    S += __shfl_xor(S, 1);
    S += __shfl_xor(S, 2);

    if (q == 0) logp[m] = tgt[m] - (M + logf(S));
}

static __device__ __forceinline__ float logsig(float z) {
    return (z >= 0.0f) ? -log1pf(expf(-z)) : (z - log1pf(expf(z)));
}

__global__ void k_loss(const float* __restrict__ logp, const int* __restrict__ y,
                       float* __restrict__ out)
{
    const int tid = threadIdx.x;
    __shared__ float sbv[4], sbc[4];
    __shared__ float seqsum[8], seqcnt[8];

    for (int s = 0; s < 8; s++) {
        const int m = s * 256 + tid;
        const int msk = (y[m] != IGNORE_INDEX) ? 1 : 0;
        float vv = msk ? logp[m] : 0.0f;
        float cc = (float)msk;
#pragma unroll
        for (int o = 32; o > 0; o >>= 1) {
            vv += __shfl_down(vv, o);
            cc += __shfl_down(cc, o);
        }
        if ((tid & 63) == 0) { sbv[tid >> 6] = vv; sbc[tid >> 6] = cc; }
        __syncthreads();
        if (tid == 0) {
            float a = 0, b = 0;
            for (int w = 0; w < 4; w++) { a += sbv[w]; b += sbc[w]; }
            seqsum[s] = a; seqcnt[s] = b;
        }
        __syncthreads();
    }
    if (tid == 0) {
        float avg[8];
        for (int s = 0; s < 8; s++) avg[s] = seqsum[s] / seqcnt[s];
        float nsum = 0, ncnt = 0;
        for (int s = 0; s < 4; s++) { nsum += seqsum[s]; ncnt += seqcnt[s]; }
        const float nll = -nsum / ncnt;
        float lsum = 0;
        for (int i = 0; i < 4; i++) {
            const float d = avg[i] - avg[i + 4] - SIMPO_GAMMA / BETA;
            const float z = BETA * d;
            lsum += logsig(z) * (1.0f - LABEL_SMOOTHING) + logsig(-z) * LABEL_SMOOTHING;
        }
        out[0] = nll * ALPHA - lsum * 0.25f;
    }
}

// ---------------------------------------------------------------------------
// Fallback GEMM (in-loop bf16 conversion, 128x128 tiles) — safety net only.
// ---------------------------------------------------------------------------
__global__ __launch_bounds__(256, 2)
void k_gemm_lse_fb(const float* __restrict__ x, const float* __restrict__ W,
                   const int* __restrict__ y,
                   float* __restrict__ pmax, float* __restrict__ psum,
                   float* __restrict__ tgt)
{
    const int bid = blockIdx.x;
    const int mt = bid & 15;
    const int vt = bid >> 4;
    const int m0 = mt * 128;
    const int v0 = vt * 128;
    const int tid = threadIdx.x;
    const int lane = tid & 63;
    const int wid = tid >> 6;
    const int wm = (wid >> 1) * 64;
    const int wv = (wid & 1) * 64;

    __shared__ short lsA[128 * 64];
    __shared__ short lsB[128 * 64];
    __shared__ int   yloc[128];
    __shared__ float wredM[4][64];
    __shared__ float wredS[4][64];

    if (tid < 128) yloc[tid] = y[m0 + tid];

    f32x4 acc[4][4];
#pragma unroll
    for (int i = 0; i < 4; i++)
#pragma unroll
        for (int j = 0; j < 4; j++) acc[i][j] = (f32x4)(0.0f);

    const int srow = tid >> 3;
    const int skb  = tid & 7;
    const float* xg = x + (size_t)m0 * Hdim;
    const float* wg = W + (size_t)v0 * Hdim;

#pragma unroll 1
    for (int kt = 0; kt < Hdim / 64; ++kt) {
        const int k0 = kt * 64;
        __syncthreads();
#pragma unroll
        for (int t = 0; t < 4; t++) {
            const int row  = t * 32 + srow;
            const int slot = skb ^ (row & 7);
            const float* pa = xg + (size_t)row * Hdim + k0 + skb * 8;
            const float* pb = wg + (size_t)row * Hdim + k0 + skb * 8;
            float4 a0 = *(const float4*)(pa);
            float4 a1 = *(const float4*)(pa + 4);
            float4 b0 = *(const float4*)(pb);
            float4 b1 = *(const float4*)(pb + 4);
            bf16x8 va, vb;
            va[0] = f2bf(a0.x); va[1] = f2bf(a0.y); va[2] = f2bf(a0.z); va[3] = f2bf(a0.w);
            va[4] = f2bf(a1.x); va[5] = f2bf(a1.y); va[6] = f2bf(a1.z); va[7] = f2bf(a1.w);
            vb[0] = f2bf(b0.x); vb[1] = f2bf(b0.y); vb[2] = f2bf(b0.z); vb[3] = f2bf(b0.w);
            vb[4] = f2bf(b1.x); vb[5] = f2bf(b1.y); vb[6] = f2bf(b1.z); vb[7] = f2bf(b1.w);
            *reinterpret_cast<bf16x8*>(&lsA[row * 64 + slot * 8]) = va;
            *reinterpret_cast<bf16x8*>(&lsB[row * 64 + slot * 8]) = vb;
        }
        __syncthreads();
#pragma unroll
        for (int ks = 0; ks < 2; ++ks) {
            bf16x8 af[4], bfr[4];
            const int kb2 = ks * 4 + (lane >> 4);
#pragma unroll
            for (int i = 0; i < 4; i++) {
                const int row = wm + i * 16 + (lane & 15);
                af[i] = *reinterpret_cast<const bf16x8*>(&lsA[row * 64 + (kb2 ^ (row & 7)) * 8]);
            }
#pragma unroll
            for (int j = 0; j < 4; j++) {
                const int row = wv + j * 16 + (lane & 15);
                bfr[j] = *reinterpret_cast<const bf16x8*>(&lsB[row * 64 + (kb2 ^ (row & 7)) * 8]);
            }
#pragma unroll
            for (int i = 0; i < 4; i++)
#pragma unroll
                for (int j = 0; j < 4; j++)
                    acc[i][j] = __builtin_amdgcn_mfma_f32_16x16x32_bf16(af[i], bfr[j], acc[i][j], 0, 0, 0);
        }
    }

    __syncthreads();
    {
        const int colbase = v0 + wv + (lane & 15);
        const int rbase = wm + ((lane >> 4) << 2);
#pragma unroll
        for (int i = 0; i < 4; i++) {
#pragma unroll
            for (int r = 0; r < 4; r++) {
                const int rloc = rbase + i * 16 + r;
                const int yv = yloc[rloc];
#pragma unroll
                for (int j = 0; j < 4; j++)
                    if (yv == colbase + j * 16) tgt[m0 + rloc] = acc[i][j][r];
            }
        }
    }
    f32x4 rm[4], rs[4];
#pragma unroll
    for (int i = 0; i < 4; i++) {
        rm[i] = acc[i][0];
#pragma unroll
        for (int j = 1; j < 4; j++) rm[i] = vmax4(rm[i], acc[i][j]);
#pragma unroll
        for (int off = 1; off < 16; off <<= 1) {
            f32x4 o;
#pragma unroll
            for (int r = 0; r < 4; r++) o[r] = __shfl_xor(rm[i][r], off);
            rm[i] = vmax4(rm[i], o);
        }
    }
#pragma unroll
    for (int i = 0; i < 4; i++) {
        f32x4 s = (f32x4)(0.0f);
#pragma unroll
        for (int j = 0; j < 4; j++)
#pragma unroll
            for (int r = 0; r < 4; r++) s[r] += expf(acc[i][j][r] - rm[i][r]);
#pragma unroll
        for (int off = 1; off < 16; off <<= 1) {
#pragma unroll
            for (int r = 0; r < 4; r++) s[r] += __shfl_xor(s[r], off);
        }
        rs[i] = s;
    }
    if ((lane & 15) == 0) {
        const int gq = lane >> 4;
#pragma unroll
        for (int i = 0; i < 4; i++)
#pragma unroll
            for (int r = 0; r < 4; r++) {
                wredM[wid][i * 16 + gq * 4 + r] = rm[i][r];
                wredS[wid][i * 16 + gq * 4 + r] = rs[i][r];
            }
    }
    __syncthreads();
    if (tid < 128) {
        const int r = tid;
        const int gh = r >> 6;
        const int rl = r & 63;
        const float ma = wredM[2 * gh][rl],  mb = wredM[2 * gh + 1][rl];
        const float sa = wredS[2 * gh][rl],  sb = wredS[2 * gh + 1][rl];
        const float M = fmaxf(ma, mb);
        const float S = sa * expf(ma - M) + sb * expf(mb - M);
        pmax[(size_t)vt * MTOK + m0 + r] = M;
        psum[(size_t)vt * MTOK + m0 + r] = S;
    }
}

// ---------------------------------------------------------------------------
extern "C" void kernel_launch(void* const* d_in, const int* in_sizes, int n_in,
                              void* d_out, int out_size, void* d_ws, size_t ws_size,
                              hipStream_t stream)
{
    const float* x = (const float*)d_in[0];
    const float* W = (const float*)d_in[1];
    const int*   y = (const int*)d_in[2];
    float* out = (float*)d_out;

    const size_t partials = (size_t)2 * NSTRIPS * MTOK * sizeof(float) + 2 * MTOK * sizeof(float);
    const size_t need = WT4_BYTES + XT4_BYTES + partials;

    if (ws_size >= need) {
        char* Wt = (char*)d_ws;
        char* Xt = Wt + WT4_BYTES;
        float* pmax = (float*)(Xt + XT4_BYTES);
        float* psum = pmax + (size_t)NSTRIPS * MTOK;
        float* tgt  = psum + (size_t)NSTRIPS * MTOK;
        float* logp = tgt + MTOK;
        k_conv4<<<dim3(17024), dim3(256), 0, stream>>>(W, x, Wt, Xt);
        k_gemm_mx4<<<dim3(NSTRIPS * NMT), dim3(256), 0, stream>>>(Wt, Xt, y, pmax, psum, tgt);
        k_finalize4<<<dim3(MTOK / 64), dim3(256), 0, stream>>>(pmax, psum, tgt, logp, NSTRIPS);
        k_loss<<<dim3(1), dim3(256), 0, stream>>>(logp, y, out);
    } else {
        float* pmax = (float*)d_ws;
        float* psum = pmax + (size_t)NSTRIPS * MTOK;
        float* tgt  = psum + (size_t)NSTRIPS * MTOK;
        float* logp = tgt + MTOK;
        k_gemm_lse_fb<<<dim3(NSTRIPS * NMT), dim3(256), 0, stream>>>(x, W, y, pmax, psum, tgt);
        k_finalize4<<<dim3(MTOK / 64), dim3(256), 0, stream>>>(pmax, psum, tgt, logp, NSTRIPS);
        k_loss<<<dim3(1), dim3(256), 0, stream>>>(logp, y, out);
    }
}

// Round 15
// 323.973 us; speedup vs baseline: 1.9391x; 1.9391x over previous
//
#include <hip/hip_runtime.h>
#include <math.h>

#define Hdim 4096
#define Vdim 32000
#define MTOK 2048
#define NSTRIPS 250        /* 32000/128 */
#define NMT 16             /* 2048/128 */
#define NKT4 32            /* 4096/128 MX K-tiles */
#define TILEF4 8192        /* 128 rows x 128 fp4 = 8 KB (64 B row stride) */

#define IGNORE_INDEX (-100)
#define BETA 0.1f
#define ALPHA 1.0f
#define SIMPO_GAMMA 0.5f
#define LABEL_SMOOTHING 0.0f

#define XSCALE 2.0f
#define WSCALE 100.0f
#define INV_SCALE (1.0f / (XSCALE * WSCALE))

#define WT4_BYTES ((size_t)NSTRIPS * NKT4 * TILEF4)  /* 65,536,000 */
#define XT4_BYTES ((size_t)NMT * NKT4 * TILEF4)      /*  4,194,304 */

typedef __attribute__((ext_vector_type(8))) short bf16x8;
typedef __attribute__((ext_vector_type(4))) float f32x4;
typedef __attribute__((ext_vector_type(8))) int i32x8;
typedef __attribute__((ext_vector_type(4))) int i32x4;

static __device__ __forceinline__ short f2bf(float f) {
    unsigned int u = __float_as_uint(f);
    u = u + 0x7fffu + ((u >> 16) & 1u);
    return (short)(u >> 16);
}

static __device__ __forceinline__ f32x4 vmax4(f32x4 a, f32x4 b) {
    f32x4 r;
    r[0] = fmaxf(a[0], b[0]); r[1] = fmaxf(a[1], b[1]);
    r[2] = fmaxf(a[2], b[2]); r[3] = fmaxf(a[3], b[3]);
    return r;
}

static __device__ __forceinline__ void gload_lds16(const void* g, void* l) {
    __builtin_amdgcn_global_load_lds(
        (const __attribute__((address_space(1))) unsigned int*)g,
        (__attribute__((address_space(3))) unsigned int*)l,
        16, 0, 0);
}

// ---- f32 -> OCP e2m1 fp4, RNE. Magnitudes {0,.5,1,1.5,2,3,4,6}. ----------
static __device__ __forceinline__ unsigned int f2e2m1(float f) {
    const unsigned s = (__float_as_uint(f) >> 28) & 0x8u;   // sign -> bit 3
    const float a = fabsf(f);
    unsigned c;
    if      (a <= 0.25f) c = 0u;
    else if (a <  0.75f) c = 1u;
    else if (a <= 1.25f) c = 2u;
    else if (a <  1.75f) c = 3u;
    else if (a <= 2.5f)  c = 4u;
    else if (a <  3.5f)  c = 5u;
    else if (a <= 5.0f)  c = 6u;
    else                 c = 7u;
    return s | c;
}

static __device__ __forceinline__ unsigned int pack8_e2m1(const float* v, float S) {
    unsigned r = 0;
#pragma unroll
    for (int i = 0; i < 8; i++) r |= f2e2m1(v[i] * S) << (4 * i);
    return r;
}

// ---------------------------------------------------------------------------
// Merged conversion: f32 -> e2m1 K-tiles (128 rows x 128 fp4 = 8 KB).
// Blocks [0, 16000): W (pre-scaled x100). Blocks [16000, 17024): x (x2).
// Row = 4 slots x 16 B (32 fp4 each); slot involution p = s ^ ((row>>1)&3)
// (64 B row stride -> round-6's measured-0-conflict bank phasing).
// ---------------------------------------------------------------------------
__global__ void k_conv4(const float* __restrict__ W, const float* __restrict__ x,
                        char* __restrict__ Wt, char* __restrict__ Xt)
{
    const unsigned int bidx = blockIdx.x;
    const float* srcbase;
    char* dstbase;
    unsigned int gc;
    float S;
    if (bidx < 16000u) {
        gc = bidx * 256 + threadIdx.x;          // < 4,096,000
        srcbase = W; dstbase = Wt; S = WSCALE;
    } else {
        gc = (bidx - 16000u) * 256 + threadIdx.x;  // < 262,144
        srcbase = x; dstbase = Xt; S = XSCALE;
    }
    const unsigned int tile = gc >> 9;          // (rt*32 + kt), 512 chunks/tile
    const unsigned int o = gc & 511u;
    const unsigned int row = o >> 2, p = o & 3u;
    const unsigned int s = p ^ ((row >> 1) & 3u);   // source k-slot (32 elems)
    const unsigned int rt = tile >> 5, kt = tile & 31u;
    const float* src = srcbase + (size_t)(rt * 128 + row) * Hdim + kt * 128 + s * 32;
    float buf[32];
#pragma unroll
    for (int i = 0; i < 8; i++)
        *reinterpret_cast<float4*>(&buf[i * 4]) = *(const float4*)(src + i * 4);
    uint4 v;
    v.x = pack8_e2m1(buf +  0, S);
    v.y = pack8_e2m1(buf +  8, S);
    v.z = pack8_e2m1(buf + 16, S);
    v.w = pack8_e2m1(buf + 24, S);
    *reinterpret_cast<uint4*>(dstbase + (size_t)tile * TILEF4 + o * 16) = v;
}

// ---------------------------------------------------------------------------
// MX-fp4 GEMM, m97 structure (measured ~2900 TF here, = m153 ladder ref):
// 128x128 tile, K-step 128, single 16 KB LDS buffer, 4 waves, 2-barrier loop,
// global_load_lds w16, 4 blocks/CU (6 spills accumulators: r14 WRITE_SIZE
// 992 MB scratch, GEMM 185->488 us — do NOT raise).
// One ds_read_b128 per fragment. mfma_scale 16x16x128 fp4 (cbsz=blgp=4),
// neutral scales. Fused LSE epilogue.
// ---------------------------------------------------------------------------
__global__ __launch_bounds__(256, 4)
void k_gemm_mx4(const char* __restrict__ Wt, const char* __restrict__ Xt,
                const int* __restrict__ y,
                float* __restrict__ pmax, float* __restrict__ psum,
                float* __restrict__ tgt)
{
    const int bid = blockIdx.x;
    // XCD-bijective swizzle: 4000 = 8 x 500, vt-major chunks per XCD.
    const int orig = (bid & 7) * 500 + (bid >> 3);
    const int vt = orig >> 4;          // 0..249
    const int mt = orig & 15;          // 0..15
    const int m0 = mt * 128, v0 = vt * 128;
    const int tid = threadIdx.x, lane = tid & 63, wid = tid >> 6;
    const int wm = (wid >> 1) * 64;
    const int wv = (wid & 1) * 64;

    __shared__ char lsA[TILEF4];
    __shared__ char lsB[TILEF4];
    __shared__ int   yloc[128];
    __shared__ float wredM[4][64];
    __shared__ float wredS[4][64];

    if (tid < 128) yloc[tid] = y[m0 + tid];

    f32x4 acc[4][4];
#pragma unroll
    for (int i = 0; i < 4; i++)
#pragma unroll
        for (int j = 0; j < 4; j++) acc[i][j] = (f32x4)(0.0f);

    const char* gA = Xt + ((size_t)mt * NKT4) * TILEF4;
    const char* gB = Wt + ((size_t)vt * NKT4) * TILEF4;

    // Per-lane LDS byte offsets: lane's k-group g = lane>>4 (32 fp4 = 16 B),
    // at physical slot (g ^ ((row>>1)&3)), 64 B rows.
    const int g = lane >> 4;
    int oA[4], oB[4];
#pragma unroll
    for (int rf = 0; rf < 4; rf++) {
        const int row = wm + rf * 16 + (lane & 15);
        oA[rf] = row * 64 + ((g ^ ((row >> 1) & 3)) << 4);
    }
#pragma unroll
    for (int cf = 0; cf < 4; cf++) {
        const int row = wv + cf * 16 + (lane & 15);
        oB[cf] = row * 64 + ((g ^ ((row >> 1) & 3)) << 4);
    }

#pragma unroll 1
    for (int kt = 0; kt < NKT4; ++kt) {
        __syncthreads();
        const char* sA = gA + (size_t)kt * TILEF4;
        const char* sB = gB + (size_t)kt * TILEF4;
        gload_lds16(sA + tid * 16,        lsA + tid * 16);
        gload_lds16(sA + 4096 + tid * 16, lsA + 4096 + tid * 16);
        gload_lds16(sB + tid * 16,        lsB + tid * 16);
        gload_lds16(sB + 4096 + tid * 16, lsB + 4096 + tid * 16);
        __syncthreads();

        i32x8 aF[4], bF[4];
#pragma unroll
        for (int rf = 0; rf < 4; rf++) {
            i32x4 d = *(const i32x4*)(lsA + oA[rf]);
            i32x8 v;
            v[0] = d[0]; v[1] = d[1]; v[2] = d[2]; v[3] = d[3];
            v[4] = 0; v[5] = 0; v[6] = 0; v[7] = 0;
            aF[rf] = v;
        }
#pragma unroll
        for (int cf = 0; cf < 4; cf++) {
            i32x4 d = *(const i32x4*)(lsB + oB[cf]);
            i32x8 v;
            v[0] = d[0]; v[1] = d[1]; v[2] = d[2]; v[3] = d[3];
            v[4] = 0; v[5] = 0; v[6] = 0; v[7] = 0;
            bF[cf] = v;
        }
#pragma unroll
        for (int rf = 0; rf < 4; rf++)
#pragma unroll
            for (int cf = 0; cf < 4; cf++)
                acc[rf][cf] = __builtin_amdgcn_mfma_scale_f32_16x16x128_f8f6f4(
                    aF[rf], bF[cf], acc[rf][cf],
                    4, 4,                 // cbsz: A=fp4, blgp: B=fp4
                    0, 0x7F7F7F7F,        // opsel_a, scale_a = 2^0
                    0, 0x7F7F7F7F);       // opsel_b, scale_b = 2^0
    }

    __syncthreads();

    // undo pre-scales (x2 * 100)
#pragma unroll
    for (int i = 0; i < 4; i++)
#pragma unroll
        for (int j = 0; j < 4; j++)
#pragma unroll
            for (int r = 0; r < 4; r++) acc[i][j][r] *= INV_SCALE;

    // ---- target-logit extraction (C layout m89: col=lane&15, row=(lane>>4)*4+r)
    {
        const int colbase = v0 + wv + (lane & 15);
        const int rbase = wm + ((lane >> 4) << 2);
#pragma unroll
        for (int i = 0; i < 4; i++) {
#pragma unroll
            for (int r = 0; r < 4; r++) {
                const int rloc = rbase + i * 16 + r;
                const int yv = yloc[rloc];
#pragma unroll
                for (int j = 0; j < 4; j++)
                    if (yv == colbase + j * 16) tgt[m0 + rloc] = acc[i][j][r];
            }
        }
    }

    // ---- per-row max / sum(exp) over this wave's 64 cols
    f32x4 rm[4], rs[4];
#pragma unroll
    for (int i = 0; i < 4; i++) {
        rm[i] = acc[i][0];
#pragma unroll
        for (int j = 1; j < 4; j++) rm[i] = vmax4(rm[i], acc[i][j]);
#pragma unroll
        for (int off = 1; off < 16; off <<= 1) {
            f32x4 o;
#pragma unroll
            for (int r = 0; r < 4; r++) o[r] = __shfl_xor(rm[i][r], off);
            rm[i] = vmax4(rm[i], o);
        }
    }
#pragma unroll
    for (int i = 0; i < 4; i++) {
        f32x4 s = (f32x4)(0.0f);
#pragma unroll
        for (int j = 0; j < 4; j++)
#pragma unroll
            for (int r = 0; r < 4; r++) s[r] += expf(acc[i][j][r] - rm[i][r]);
#pragma unroll
        for (int off = 1; off < 16; off <<= 1) {
#pragma unroll
            for (int r = 0; r < 4; r++) s[r] += __shfl_xor(s[r], off);
        }
        rs[i] = s;
    }
    if ((lane & 15) == 0) {
        const int gq = lane >> 4;
#pragma unroll
        for (int i = 0; i < 4; i++)
#pragma unroll
            for (int r = 0; r < 4; r++) {
                wredM[wid][i * 16 + gq * 4 + r] = rm[i][r];
                wredS[wid][i * 16 + gq * 4 + r] = rs[i][r];
            }
    }
    __syncthreads();
    if (tid < 128) {
        const int r = tid;
        const int gh = r >> 6;
        const int rl = r & 63;
        const float ma = wredM[2 * gh][rl],  mb = wredM[2 * gh + 1][rl];
        const float sa = wredS[2 * gh][rl],  sb = wredS[2 * gh + 1][rl];
        const float M = fmaxf(ma, mb);
        const float S = sa * expf(ma - M) + sb * expf(mb - M);
        pmax[(size_t)vt * MTOK + m0 + r] = M;
        psum[(size_t)vt * MTOK + m0 + r] = S;
    }
}

// ---------------------------------------------------------------------------
// Finalize: 4 lanes per token (two-phase max/sum, shfl_xor merge).
// grid 32 x 256: block handles 64 tokens.
// ---------------------------------------------------------------------------
__global__ void k_finalize4(const float* __restrict__ pmax, const float* __restrict__ psum,
                            const float* __restrict__ tgt, float* __restrict__ logp,
                            int nstrips)
{
    const int tid = threadIdx.x;
    const int m = blockIdx.x * 64 + (tid >> 2);   // token
    const int q = tid & 3;                        // lane's strip phase
    if (m >= MTOK) return;

    float M = -INFINITY;
    for (int s = q; s < nstrips; s += 4) M = fmaxf(M, pmax[(size_t)s * MTOK + m]);
    M = fmaxf(M, __shfl_xor(M, 1));
    M = fmaxf(M, __shfl_xor(M, 2));

    float S = 0.0f;
    for (int s = q; s < nstrips; s += 4)
        S += psum[(size_t)s * MTOK + m] * expf(pmax[(size_t)s * MTOK + m] - M);
    S += __shfl_xor(S, 1);
    S += __shfl_xor(S, 2);

    if (q == 0) logp[m] = tgt[m] - (M + logf(S));
}

static __device__ __forceinline__ float logsig(float z) {
    return (z >= 0.0f) ? -log1pf(expf(-z)) : (z - log1pf(expf(z)));
}

__global__ void k_loss(const float* __restrict__ logp, const int* __restrict__ y,
                       float* __restrict__ out)
{
    const int tid = threadIdx.x;
    __shared__ float sbv[4], sbc[4];
    __shared__ float seqsum[8], seqcnt[8];

    for (int s = 0; s < 8; s++) {
        const int m = s * 256 + tid;
        const int msk = (y[m] != IGNORE_INDEX) ? 1 : 0;
        float vv = msk ? logp[m] : 0.0f;
        float cc = (float)msk;
#pragma unroll
        for (int o = 32; o > 0; o >>= 1) {
            vv += __shfl_down(vv, o);
            cc += __shfl_down(cc, o);
        }
        if ((tid & 63) == 0) { sbv[tid >> 6] = vv; sbc[tid >> 6] = cc; }
        __syncthreads();
        if (tid == 0) {
            float a = 0, b = 0;
            for (int w = 0; w < 4; w++) { a += sbv[w]; b += sbc[w]; }
            seqsum[s] = a; seqcnt[s] = b;
        }
        __syncthreads();
    }
    if (tid == 0) {
        float avg[8];
        for (int s = 0; s < 8; s++) avg[s] = seqsum[s] / seqcnt[s];
        float nsum = 0, ncnt = 0;
        for (int s = 0; s < 4; s++) { nsum += seqsum[s]; ncnt += seqcnt[s]; }
        const float nll = -nsum / ncnt;
        float lsum = 0;
        for (int i = 0; i < 4; i++) {
            const float d = avg[i] - avg[i + 4] - SIMPO_GAMMA / BETA;
            const float z = BETA * d;
            lsum += logsig(z) * (1.0f - LABEL_SMOOTHING) + logsig(-z) * LABEL_SMOOTHING;
        }
        out[0] = nll * ALPHA - lsum * 0.25f;
    }
}

// ---------------------------------------------------------------------------
// Fallback GEMM (in-loop bf16 conversion, 128x128 tiles) — safety net only.
// ---------------------------------------------------------------------------
__global__ __launch_bounds__(256, 2)
void k_gemm_lse_fb(const float* __restrict__ x, const float* __restrict__ W,
                   const int* __restrict__ y,
                   float* __restrict__ pmax, float* __restrict__ psum,
                   float* __restrict__ tgt)
{
    const int bid = blockIdx.x;
    const int mt = bid & 15;
    const int vt = bid >> 4;
    const int m0 = mt * 128;
    const int v0 = vt * 128;
    const int tid = threadIdx.x;
    const int lane = tid & 63;
    const int wid = tid >> 6;
    const int wm = (wid >> 1) * 64;
    const int wv = (wid & 1) * 64;

    __shared__ short lsA[128 * 64];
    __shared__ short lsB[128 * 64];
    __shared__ int   yloc[128];
    __shared__ float wredM[4][64];
    __shared__ float wredS[4][64];

    if (tid < 128) yloc[tid] = y[m0 + tid];

    f32x4 acc[4][4];
#pragma unroll
    for (int i = 0; i < 4; i++)
#pragma unroll
        for (int j = 0; j < 4; j++) acc[i][j] = (f32x4)(0.0f);

    const int srow = tid >> 3;
    const int skb  = tid & 7;
    const float* xg = x + (size_t)m0 * Hdim;
    const float* wg = W + (size_t)v0 * Hdim;

#pragma unroll 1
    for (int kt = 0; kt < Hdim / 64; ++kt) {
        const int k0 = kt * 64;
        __syncthreads();
#pragma unroll
        for (int t = 0; t < 4; t++) {
            const int row  = t * 32 + srow;
            const int slot = skb ^ (row & 7);
            const float* pa = xg + (size_t)row * Hdim + k0 + skb * 8;
            const float* pb = wg + (size_t)row * Hdim + k0 + skb * 8;
            float4 a0 = *(const float4*)(pa);
            float4 a1 = *(const float4*)(pa + 4);
            float4 b0 = *(const float4*)(pb);
            float4 b1 = *(const float4*)(pb + 4);
            bf16x8 va, vb;
            va[0] = f2bf(a0.x); va[1] = f2bf(a0.y); va[2] = f2bf(a0.z); va[3] = f2bf(a0.w);
            va[4] = f2bf(a1.x); va[5] = f2bf(a1.y); va[6] = f2bf(a1.z); va[7] = f2bf(a1.w);
            vb[0] = f2bf(b0.x); vb[1] = f2bf(b0.y); vb[2] = f2bf(b0.z); vb[3] = f2bf(b0.w);
            vb[4] = f2bf(b1.x); vb[5] = f2bf(b1.y); vb[6] = f2bf(b1.z); vb[7] = f2bf(b1.w);
            *reinterpret_cast<bf16x8*>(&lsA[row * 64 + slot * 8]) = va;
            *reinterpret_cast<bf16x8*>(&lsB[row * 64 + slot * 8]) = vb;
        }
        __syncthreads();
#pragma unroll
        for (int ks = 0; ks < 2; ++ks) {
            bf16x8 af[4], bfr[4];
            const int kb2 = ks * 4 + (lane >> 4);
#pragma unroll
            for (int i = 0; i < 4; i++) {
                const int row = wm + i * 16 + (lane & 15);
                af[i] = *reinterpret_cast<const bf16x8*>(&lsA[row * 64 + (kb2 ^ (row & 7)) * 8]);
            }
#pragma unroll
            for (int j = 0; j < 4; j++) {
                const int row = wv + j * 16 + (lane & 15);
                bfr[j] = *reinterpret_cast<const bf16x8*>(&lsB[row * 64 + (kb2 ^ (row & 7)) * 8]);
            }
#pragma unroll
            for (int i = 0; i < 4; i++)
#pragma unroll
                for (int j = 0; j < 4; j++)
                    acc[i][j] = __builtin_amdgcn_mfma_f32_16x16x32_bf16(af[i], bfr[j], acc[i][j], 0, 0, 0);
        }
    }

    __syncthreads();
    {
        const int colbase = v0 + wv + (lane & 15);
        const int rbase = wm + ((lane >> 4) << 2);
#pragma unroll
        for (int i = 0; i < 4; i++) {
#pragma unroll
            for (int r = 0; r < 4; r++) {
                const int rloc = rbase + i * 16 + r;
                const int yv = yloc[rloc];
#pragma unroll
                for (int j = 0; j < 4; j++)
                    if (yv == colbase + j * 16) tgt[m0 + rloc] = acc[i][j][r];
            }
        }
    }
    f32x4 rm[4], rs[4];
#pragma unroll
    for (int i = 0; i < 4; i++) {
        rm[i] = acc[i][0];
#pragma unroll
        for (int j = 1; j < 4; j++) rm[i] = vmax4(rm[i], acc[i][j]);
#pragma unroll
        for (int off = 1; off < 16; off <<= 1) {
            f32x4 o;
#pragma unroll
            for (int r = 0; r < 4; r++) o[r] = __shfl_xor(rm[i][r], off);
            rm[i] = vmax4(rm[i], o);
        }
    }
#pragma unroll
    for (int i = 0; i < 4; i++) {
        f32x4 s = (f32x4)(0.0f);
#pragma unroll
        for (int j = 0; j < 4; j++)
#pragma unroll
            for (int r = 0; r < 4; r++) s[r] += expf(acc[i][j][r] - rm[i][r]);
#pragma unroll
        for (int off = 1; off < 16; off <<= 1) {
#pragma unroll
            for (int r = 0; r < 4; r++) s[r] += __shfl_xor(s[r], off);
        }
        rs[i] = s;
    }
    if ((lane & 15) == 0) {
        const int gq = lane >> 4;
#pragma unroll
        for (int i = 0; i < 4; i++)
#pragma unroll
            for (int r = 0; r < 4; r++) {
                wredM[wid][i * 16 + gq * 4 + r] = rm[i][r];
                wredS[wid][i * 16 + gq * 4 + r] = rs[i][r];
            }
    }
    __syncthreads();
    if (tid < 128) {
        const int r = tid;
        const int gh = r >> 6;
        const int rl = r & 63;
        const float ma = wredM[2 * gh][rl],  mb = wredM[2 * gh + 1][rl];
        const float sa = wredS[2 * gh][rl],  sb = wredS[2 * gh + 1][rl];
        const float M = fmaxf(ma, mb);
        const float S = sa * expf(ma - M) + sb * expf(mb - M);
        pmax[(size_t)vt * MTOK + m0 + r] = M;
        psum[(size_t)vt * MTOK + m0 + r] = S;
    }
}

// ---------------------------------------------------------------------------
extern "C" void kernel_launch(void* const* d_in, const int* in_sizes, int n_in,
                              void* d_out, int out_size, void* d_ws, size_t ws_size,
                              hipStream_t stream)
{
    const float* x = (const float*)d_in[0];
    const float* W = (const float*)d_in[1];
    const int*   y = (const int*)d_in[2];
    float* out = (float*)d_out;

    const size_t partials = (size_t)2 * NSTRIPS * MTOK * sizeof(float) + 2 * MTOK * sizeof(float);
    const size_t need = WT4_BYTES + XT4_BYTES + partials;

    if (ws_size >= need) {
        char* Wt = (char*)d_ws;
        char* Xt = Wt + WT4_BYTES;
        float* pmax = (float*)(Xt + XT4_BYTES);
        float* psum = pmax + (size_t)NSTRIPS * MTOK;
        float* tgt  = psum + (size_t)NSTRIPS * MTOK;
        float* logp = tgt + MTOK;
        k_conv4<<<dim3(17024), dim3(256), 0, stream>>>(W, x, Wt, Xt);
        k_gemm_mx4<<<dim3(NSTRIPS * NMT), dim3(256), 0, stream>>>(Wt, Xt, y, pmax, psum, tgt);
        k_finalize4<<<dim3(MTOK / 64), dim3(256), 0, stream>>>(pmax, psum, tgt, logp, NSTRIPS);
        k_loss<<<dim3(1), dim3(256), 0, stream>>>(logp, y, out);
    } else {
        float* pmax = (float*)d_ws;
        float* psum = pmax + (size_t)NSTRIPS * MTOK;
        float* tgt  = psum + (size_t)NSTRIPS * MTOK;
        float* logp = tgt + MTOK;
        k_gemm_lse_fb<<<dim3(NSTRIPS * NMT), dim3(256), 0, stream>>>(x, W, y, pmax, psum, tgt);
        k_finalize4<<<dim3(MTOK / 64), dim3(256), 0, stream>>>(pmax, psum, tgt, logp, NSTRIPS);
        k_loss<<<dim3(1), dim3(256), 0, stream>>>(logp, y, out);
    }
}